// Round 1
// 350.319 us; speedup vs baseline: 1.2558x; 1.2558x over previous
//
#include <hip/hip_runtime.h>
#include <math.h>

// ---------------------------------------------------------------------------
// Prototypical network forward on MI355X.
// Round 3: conv1 moved from scalar fp32 VALU to MFMA (2x 16x16x32 per tile,
// K-mapped so B-gather = two 8B LDS reads from a ch-padded bf16 staging
// buffer). All bf16 pack stores use native __bf16 casts -> v_cvt_pk_bf16_f32.
//   image slots: [0,160) sup | [160,320) sup flipped | [320,800) pro(sup+qry)
// ---------------------------------------------------------------------------

typedef __attribute__((ext_vector_type(8))) short bf16x8;
typedef __attribute__((ext_vector_type(8))) unsigned short u16x8;
typedef __attribute__((ext_vector_type(4))) float f32x4;
typedef unsigned short u16;
typedef unsigned int u32;

#define PIX84 (84 * 84)      // 7056
#define D     (21 * 21 * 16) // 7056
#define WF_C1 17920          // offset (u16) of conv1 A-fragments in wf

__device__ __forceinline__ float bf2f(u16 v) {
    union { u32 i; float f; } c; c.i = ((u32)v) << 16; return c.f;
}
__device__ __forceinline__ u16 f2bf(float f) {
    union { float f; u32 i; } c; c.f = f;
    u32 r = c.i + 0x7fffu + ((c.i >> 16) & 1u);
    return (u16)(r >> 16);
}
// Native bf16 pair conversion: compiler emits v_cvt_pk_bf16_f32 (RNE).
__device__ __forceinline__ u32 pack2(float a, float b) {
    union { __bf16 h[2]; u32 u; } p;
    p.h[0] = (__bf16)a; p.h[1] = (__bf16)b;
    return p.u;
}

// LDS layout: channel ch of pixel P lives at byte swz(P, ch>=8) + (ch&7)*2.
// XOR of granule-half with bit2(P) spreads stride-32B wave accesses across
// all 8 granule classes -> 2-way (free) instead of 4-way bank conflicts.
__device__ __forceinline__ int swz(int P, int h) {
    return P * 32 + ((h ^ ((P >> 2) & 1)) << 4);
}

// 16B LDS load with only 8B alignment guarantee (ds_read2_b64).
__device__ __forceinline__ bf16x8 ld_bf16x8_a8(const char* p) {
    union { uint2 q[2]; bf16x8 v; } u;
    u.q[0] = *(const uint2*)(p);
    u.q[1] = *(const uint2*)(p + 8);
    return u.v;
}

__device__ __forceinline__ float blockReduceSum(float v) {
    __shared__ float red[8];
    #pragma unroll
    for (int o = 32; o > 0; o >>= 1) v += __shfl_down(v, o, 64);
    const int lane = threadIdx.x & 63, wid = threadIdx.x >> 6;
    __syncthreads();
    if (lane == 0) red[wid] = v;
    __syncthreads();
    float r = 0.f;
    if (threadIdx.x == 0) {
        const int nw = (blockDim.x + 63) >> 6;
        for (int i = 0; i < nw; ++i) r += red[i];
    }
    return r;
}

// Pack conv2..conv8 weights (HWIO [tap][ci][co]) into MFMA A-fragment layout.
// wf[L][s][lane][j]: lane -> co = lane&15, g = lane>>4; k = 8g+j;
// tap = 2s + (k>>4), ci = k&15; zero for tap > 8 (K padded 144 -> 160).
// conv1 frags at WF_C1: 2 MFMAs, k = dh*16 + dw*4 + ci (m0: dh 0/1, m1: dh 2),
// zero weight on padded slots (ci==3, dw==3, m1 k>=12).
__global__ void prep_weights(const float* __restrict__ k1, const float* __restrict__ k2,
                             const float* __restrict__ k3, const float* __restrict__ k4,
                             const float* __restrict__ k5, const float* __restrict__ k6,
                             const float* __restrict__ k7, const float* __restrict__ k8,
                             u16* __restrict__ wf)
{
    const int idx = blockIdx.x * 256 + threadIdx.x;
    if (idx < WF_C1) {
        const int j = idx & 7, lane = (idx >> 3) & 63, r = idx >> 9;
        const int s = r % 5, L = r / 5;
        const float* ks[7] = { k2, k3, k4, k5, k6, k7, k8 };
        const int co = lane & 15, g = lane >> 4;
        const int k = g * 8 + j, tap = 2 * s + (k >> 4), ci = k & 15;
        const float v = (tap <= 8) ? ks[L][(tap * 16 + ci) * 16 + co] : 0.f;
        wf[idx] = f2bf(v);
    } else if (idx < WF_C1 + 1024) {
        const int t = idx - WF_C1;
        const int j = t & 7, lane = (t >> 3) & 63, m = t >> 9;
        const int co = lane & 15, g = lane >> 4;
        const int k = g * 8 + j;
        const int dh  = (m == 0) ? (k >> 4) : 2;
        const int rem = (m == 0) ? (k & 15) : k;
        const int dw = rem >> 2, ci = rem & 3;
        const float v = (rem < 12 && ci < 3) ? k1[((dh * 3 + dw) * 3 + ci) * 16 + co] : 0.f;
        wf[idx] = f2bf(v);
    }
}

// One 16ch->16ch conv layer, MFMA, in-place in the (swizzled) LDS buffer.
// Each wave holds its full set of output tiles in registers across a barrier.
// Reads src rows [0, nrows+2) at (j+dh, w+dw); writes rows [dro, dro+nrows).
template <int W, int LW, int MAXT>
__device__ __forceinline__ void conv_layer(char* buf, const u16* wfL,
                                           const float* bias, float scale,
                                           int nrows, int dro, int lane, int wv)
{
    const int g = lane >> 4, col = lane & 15;
    bf16x8 wfr[5];
    #pragma unroll
    for (int s = 0; s < 5; ++s) wfr[s] = ((const bf16x8*)wfL)[s * 64 + lane];
    const float4 bv = *(const float4*)(bias + g * 4);
    const int NPX = nrows * W;
    const int TC = (NPX + 15) >> 4;
    const int t0 = wv * MAXT;

    f32x4 acc[MAXT];
    #pragma unroll
    for (int u = 0; u < MAXT; ++u) {
        const int t = t0 + u;
        if (t < TC) {
            const int px = t * 16 + col;
            const int p = (px < NPX) ? px : 0;
            const int j = p / W, w = p - j * W;
            f32x4 a = { 0.f, 0.f, 0.f, 0.f };
            #pragma unroll
            for (int s = 0; s < 5; ++s) {
                int tap = 2 * s + (g >> 1);
                tap = (tap > 8) ? 8 : tap;   // padded tap: A-side weights are zero
                const int dh = tap / 3, dw = tap - dh * 3;
                const bf16x8 bfrag =
                    *(const bf16x8*)(buf + swz((j + dh) * LW + (w + dw), g & 1));
                a = __builtin_amdgcn_mfma_f32_16x16x32_bf16(wfr[s], bfrag, a, 0, 0, 0);
            }
            acc[u] = a;
        }
    }
    __syncthreads();   // all reads done before any in-place write
    #pragma unroll
    for (int u = 0; u < MAXT; ++u) {
        const int t = t0 + u;
        if (t < TC) {
            const int px = t * 16 + col;
            if (px < NPX) {
                const int j = px / W, w = px - j * W;
                const u32 lo = pack2((acc[u][0] + bv.x) * scale,
                                     (acc[u][1] + bv.y) * scale);
                const u32 hi = pack2((acc[u][2] + bv.z) * scale,
                                     (acc[u][3] + bv.w) * scale);
                *(uint2*)(buf + swz((j + dro) * LW + (w + 1), g >> 1) + (g & 1) * 8) =
                    make_uint2(lo, hi);
            }
        }
    }
    __syncthreads();
}

// stage1: conv1(MFMA) + conv2/3/4(MFMA) + bn/relu/pool -> s1out (42x42x16 bf16)
// grid: img * 6 strips (7 pooled rows each). Single 20x86 LDS buffer, in-place.
__global__ __launch_bounds__(512) void stage1_kernel(
    const float* __restrict__ sup, const float* __restrict__ qry,
    const float* __restrict__ b1,
    const u16* __restrict__ wf,
    const float* __restrict__ b2, const float* __restrict__ b3,
    const float* __restrict__ b4,
    const float* __restrict__ g1, const float* __restrict__ be1,
    const float* __restrict__ Wm,
    u16* __restrict__ s1out)
{
    __shared__ char buf[20 * 86 * 32];          // 55,040 B
    __shared__ u16 stag[(22 * 86 + 2) * 4];     // 15,152 B raw input, ch padded to 4
    const int img = blockIdx.x / 6, bb = blockIdx.x % 6;
    const int R0 = 14 * bb;              // base c4-row of this strip
    const int tid = threadIdx.x, lane = tid & 63, wv = tid >> 6;
    const bool pro = img >= 320;

    const float* src;
    bool flip = false;
    if (img < 160) src = sup + (size_t)img * (PIX84 * 3);
    else if (img < 320) { src = sup + (size_t)(img - 160) * (PIX84 * 3); flip = true; }
    else {
        const int m = img - 320;
        src = (m < 160) ? sup + (size_t)m * (PIX84 * 3)
                        : qry + (size_t)(m - 160) * (PIX84 * 3);
    }
    const float s1 = pro ? Wm[0] : 1.f, s2 = pro ? Wm[1] : 1.f;
    const float s3 = pro ? Wm[2] : 1.f, s4 = pro ? Wm[3] : 1.f;
    const float pre = pro ? Wm[4] : 1.f, rs = pro ? Wm[5] : 1.f;
    const float post = pro ? Wm[6] : 1.f;

    // zero border columns of conv buffer (rows 0..19, cols 0 & 85)
    for (int i = tid; i < 40; i += 512) {
        const int P = (i >> 1) * 86 + ((i & 1) ? 85 : 0);
        *(uint4*)(buf + swz(P, 0)) = make_uint4(0, 0, 0, 0);
        *(uint4*)(buf + swz(P, 1)) = make_uint4(0, 0, 0, 0);
    }

    // stage raw input rows R0-4 .. R0+17 as bf16, zero-padded borders.
    // stag px (r,c): input row hin=R0-4+r, col win=c-1; 4 u16/px (3 ch + pad).
    for (int p = tid; p < 22 * 86; p += 512) {
        const int r = p / 86, c = p - r * 86;
        const int hin = R0 - 4 + r, win = c - 1;
        u32 lo = 0, hi = 0;
        if ((unsigned)hin < 84u && (unsigned)win < 84u) {
            const int wsrc = flip ? (83 - win) : win;
            const float* ip = src + ((size_t)(hin * 84 + wsrc)) * 3;
            lo = pack2(ip[0], ip[1]);
            hi = pack2(ip[2], 0.f);
        }
        *(uint2*)((char*)stag + (size_t)p * 8) = make_uint2(lo, hi);
    }
    __syncthreads();

    // conv1 via MFMA: 105 tiles of 16 px. B-fragment per lane = two 8B reads:
    // m0 covers patch rows dh=0,1 (k=dh*16+dw*4+ci), m1 covers dh=2.
    {
        const int g = lane >> 4, col = lane & 15;
        const bf16x8 wA0 = ((const bf16x8*)(wf + WF_C1))[lane];
        const bf16x8 wA1 = ((const bf16x8*)(wf + WF_C1))[64 + lane];
        const float4 bv = *(const float4*)(b1 + g * 4);
        const int off0 = ((g >> 1) * 86 + (g & 1) * 2) * 8;
        const int off1 = (2 * 86 + (g & 1) * 2) * 8;
        for (int t = wv; t < 105; t += 8) {
            const int p = t * 16 + col;          // 105*16 == 20*84 exactly
            const int ri = p / 84, w = p - ri * 84;
            const int base = (ri * 86 + w) * 8;
            const bf16x8 B0 = ld_bf16x8_a8((const char*)stag + base + off0);
            const bf16x8 B1 = ld_bf16x8_a8((const char*)stag + base + off1);
            f32x4 a = { 0.f, 0.f, 0.f, 0.f };
            a = __builtin_amdgcn_mfma_f32_16x16x32_bf16(wA0, B0, a, 0, 0, 0);
            a = __builtin_amdgcn_mfma_f32_16x16x32_bf16(wA1, B1, a, 0, 0, 0);
            const int h = R0 - 3 + ri;
            const float sc = ((unsigned)h < 84u) ? s1 : 0.f;  // OOB rows -> exact 0
            const u32 lo = pack2((a[0] + bv.x) * sc, (a[1] + bv.y) * sc);
            const u32 hi = pack2((a[2] + bv.z) * sc, (a[3] + bv.w) * sc);
            *(uint2*)(buf + swz(ri * 86 + (w + 1), g >> 1) + (g & 1) * 8) =
                make_uint2(lo, hi);
        }
    }
    __syncthreads();

    conv_layer<84, 86, 12>(buf, wf,        b2, s2, 18, 0, lane, wv);  // c2
    conv_layer<84, 86, 11>(buf, wf + 2560, b3, s3, 16, 0, lane, wv);  // c3
    conv_layer<84, 86, 10>(buf, wf + 5120, b4, s4, 14, 0, lane, wv);  // c4

    // bn + relu + 2x2 pool (scale-inside-max for sign-correctness) -> global
    for (int e = tid; e < 7 * 42 * 2; e += 512) {
        const int hf = e & 1;
        const int pc = (e >> 1) % 42, pr = (e >> 1) / 42;
        float mx[8];
        #pragma unroll
        for (int c = 0; c < 8; ++c) mx[c] = -1e30f;
        #pragma unroll
        for (int dy = 0; dy < 2; ++dy)
            #pragma unroll
            for (int dx = 0; dx < 2; ++dx) {
                const int P = (2 * pr + dy) * 86 + (2 * pc + dx + 1);
                const u16x8 vv = *(const u16x8*)(buf + swz(P, hf));
                #pragma unroll
                for (int c = 0; c < 8; ++c) {
                    const int ch = hf * 8 + c;
                    const float t =
                        rs * fmaxf(0.f, pre * fmaf(g1[ch], bf2f(vv[c]), be1[ch]));
                    mx[c] = fmaxf(mx[c], t);
                }
            }
        uint4 o;
        o.x = pack2(post * mx[0], post * mx[1]);
        o.y = pack2(post * mx[2], post * mx[3]);
        o.z = pack2(post * mx[4], post * mx[5]);
        o.w = pack2(post * mx[6], post * mx[7]);
        *(uint4*)(s1out + (size_t)img * 28224 +
                  ((size_t)(7 * bb + pr) * 42 + pc) * 16 + hf * 8) = o;
    }
}

// stage2: whole 42x42 image in LDS; conv5..8 in-place; bn+pool -> z/zp (f32)
__global__ __launch_bounds__(512) void stage2_kernel(
    const u16* __restrict__ s1in, const u16* __restrict__ wf,
    const float* __restrict__ b5, const float* __restrict__ b6,
    const float* __restrict__ b7, const float* __restrict__ b8,
    const float* __restrict__ g2, const float* __restrict__ be2,
    const float* __restrict__ Wm,
    float* __restrict__ z, float* __restrict__ zp)
{
    __shared__ char buf[44 * 44 * 32];   // 61,952 B
    const int img = blockIdx.x;
    const int tid = threadIdx.x, lane = tid & 63, wv = tid >> 6;
    const bool pro = img >= 320;
    const float s5 = pro ? Wm[7] : 1.f, s6 = pro ? Wm[8] : 1.f;
    const float s7 = pro ? Wm[9] : 1.f, s8 = pro ? Wm[10] : 1.f;
    const float pre = pro ? Wm[11] : 1.f, rs = pro ? Wm[12] : 1.f;
    const float post = pro ? (Wm[13] * Wm[14]) : 1.f;

    // zero border ring
    for (int i = tid; i < 44 * 44; i += 512) {
        const int r = i / 44, c = i - r * 44;
        if (r == 0 || r == 43 || c == 0 || c == 43) {
            *(uint4*)(buf + swz(i, 0)) = make_uint4(0, 0, 0, 0);
            *(uint4*)(buf + swz(i, 1)) = make_uint4(0, 0, 0, 0);
        }
    }
    // load 42x42x16 bf16 input into interior
    const u16* ip = s1in + (size_t)img * 28224;
    for (int cix = tid; cix < 42 * 42 * 2; cix += 512) {
        const int Pi = cix >> 1, hf = cix & 1;
        const int r = Pi / 42, c = Pi - r * 42;
        const uint4 v = *(const uint4*)(ip + (size_t)cix * 8);
        *(uint4*)(buf + swz((r + 1) * 44 + (c + 1), hf)) = v;
    }
    __syncthreads();

    conv_layer<42, 44, 14>(buf, wf + 3 * 2560, b5, s5, 42, 1, lane, wv);  // c5
    conv_layer<42, 44, 14>(buf, wf + 4 * 2560, b6, s6, 42, 1, lane, wv);  // c6
    conv_layer<42, 44, 14>(buf, wf + 5 * 2560, b7, s7, 42, 1, lane, wv);  // c7
    conv_layer<42, 44, 14>(buf, wf + 6 * 2560, b8, s8, 42, 1, lane, wv);  // c8

    float* outp = pro ? (zp + (size_t)(img - 320) * D) : (z + (size_t)img * D);
    for (int e = tid; e < 21 * 21 * 2; e += 512) {
        const int hf = e & 1;
        const int pc = (e >> 1) % 21, pr = (e >> 1) / 21;
        float mx[8];
        #pragma unroll
        for (int c = 0; c < 8; ++c) mx[c] = -1e30f;
        #pragma unroll
        for (int dy = 0; dy < 2; ++dy)
            #pragma unroll
            for (int dx = 0; dx < 2; ++dx) {
                const int P = (2 * pr + dy + 1) * 44 + (2 * pc + dx + 1);
                const u16x8 vv = *(const u16x8*)(buf + swz(P, hf));
                #pragma unroll
                for (int c = 0; c < 8; ++c) {
                    const int ch = hf * 8 + c;
                    const float t =
                        rs * fmaxf(0.f, pre * fmaf(g2[ch], bf2f(vv[c]), be2[ch]));
                    mx[c] = fmaxf(mx[c], t);
                }
            }
        float* op = outp + ((size_t)(pr * 21 + pc)) * 16 + hf * 8;
        float4 o0 = make_float4(post * mx[0], post * mx[1], post * mx[2], post * mx[3]);
        float4 o1 = make_float4(post * mx[4], post * mx[5], post * mx[6], post * mx[7]);
        *(float4*)op = o0;
        *(float4*)(op + 4) = o1;
    }
}

// Pairwise (mean squared distance)^2 over z (320 f32 rows).
__global__ void pairs_kernel(const float* __restrict__ z,
                             float* __restrict__ within, float* __restrict__ cross,
                             float* __restrict__ aug)
{
    const int bid = blockIdx.x;
    const float *u, *v;
    float* dst;
    if (bid < 1280) {
        const int c = bid / 64, i = (bid % 64) / 8, j = bid % 8;
        u = z + (size_t)(c * 8 + i) * D;
        v = z + (size_t)(c * 8 + j) * D;
        dst = within + bid;
    } else if (bid < 2560) {
        const int t = bid - 1280;
        const int c = t / 64, i = (t % 64) / 8, j = t % 8;
        const int c2 = (c + 1) % 20;
        u = z + (size_t)(c * 8 + i) * D;
        v = z + (size_t)(c2 * 8 + j) * D;
        dst = cross + t;
    } else {
        const int t = bid - 2560;
        u = z + (size_t)t * D;
        v = z + (size_t)(160 + t) * D;
        dst = aug + t;
    }
    const float4* u4 = (const float4*)u;
    const float4* v4 = (const float4*)v;
    float s = 0.f;
    for (int d = threadIdx.x; d < D / 4; d += 256) {
        const float4 a = u4[d], b = v4[d];
        const float dx = a.x - b.x, dy = a.y - b.y, dz = a.z - b.z, dw = a.w - b.w;
        s += dx * dx + dy * dy + dz * dz + dw * dw;
    }
    s = blockReduceSum(s);
    if (threadIdx.x == 0) {
        const float m = s / (float)D;
        *dst = m * m;
    }
}

__global__ void protos_kernel(const float* __restrict__ zp, float* __restrict__ protos)
{
    const int idx = blockIdx.x * 256 + threadIdx.x;
    if (idx >= 20 * D) return;
    const int c = idx / D, d = idx % D;
    float s = 0.f;
    #pragma unroll
    for (int i = 0; i < 8; ++i) s += zp[(size_t)(c * 8 + i) * D + d];
    protos[idx] = s * 0.125f;
}

__global__ void dists_kernel(const float* __restrict__ zq, const float* __restrict__ protos,
                             float* __restrict__ dists)
{
    const int q = blockIdx.x / 20, c = blockIdx.x % 20;
    const float4* u4 = (const float4*)(zq + (size_t)q * D);
    const float4* v4 = (const float4*)(protos + (size_t)c * D);
    float s = 0.f;
    for (int d = threadIdx.x; d < D / 4; d += 256) {
        const float4 a = u4[d], b = v4[d];
        const float dx = a.x - b.x, dy = a.y - b.y, dz = a.z - b.z, dw = a.w - b.w;
        s += dx * dx + dy * dy + dz * dz + dw * dw;
    }
    s = blockReduceSum(s);
    if (threadIdx.x == 0) dists[blockIdx.x] = s / (float)D;
}

__global__ void final_kernel(const float* __restrict__ dists,
                             const float* __restrict__ within,
                             const float* __restrict__ cross,
                             const float* __restrict__ aug,
                             float* __restrict__ out)
{
    float ce = 0.f, accv = 0.f, uns = 0.f;
    for (int r = threadIdx.x; r < 320; r += 256) {
        const float* dr = dists + r * 20;
        const int y = r / 16;
        float dmin = dr[0];
        int amin = 0;
        float m = -dr[0];
        #pragma unroll
        for (int j = 1; j < 20; ++j) {
            if (dr[j] < dmin) { dmin = dr[j]; amin = j; }
            m = fmaxf(m, -dr[j]);
        }
        float se = 0.f;
        #pragma unroll
        for (int j = 0; j < 20; ++j) se += expf(-dr[j] - m);
        const float lse = m + logf(se);
        ce += dr[y] + lse;
        accv += (amin == y) ? 1.0f : 0.0f;
    }
    for (int i = threadIdx.x; i < 1280; i += 256) uns += within[i] - cross[i];
    for (int i = threadIdx.x; i < 160; i += 256) uns += aug[i];

    ce = blockReduceSum(ce);
    accv = blockReduceSum(accv);
    uns = blockReduceSum(uns);
    if (threadIdx.x == 0) {
        out[0] = ce / 320.0f + uns / 17.0f + 80.0f;   // 0.5 * 160
        out[1] = accv / 320.0f;
    }
}

extern "C" void kernel_launch(void* const* d_in, const int* in_sizes, int n_in,
                              void* d_out, int out_size, void* d_ws, size_t ws_size,
                              hipStream_t stream)
{
    (void)in_sizes; (void)n_in; (void)out_size; (void)ws_size;
    const float* sup = (const float*)d_in[0];
    const float* qry = (const float*)d_in[1];
    const float* K[8]; for (int i = 0; i < 8; ++i) K[i] = (const float*)d_in[2 + i];
    const float* B[8]; for (int i = 0; i < 8; ++i) B[i] = (const float*)d_in[10 + i];
    const float* g1  = (const float*)d_in[18];
    const float* be1 = (const float*)d_in[19];
    const float* g2  = (const float*)d_in[20];
    const float* be2 = (const float*)d_in[21];
    const float* Wm  = (const float*)d_in[22];
    float* out = (float*)d_out;

    // ---- workspace carve-up (~68 MB total) ----
    size_t off = 0;
    auto alloc = [&](size_t bytes) -> void* {
        void* p = (char*)d_ws + off;
        off += (bytes + 255) & ~(size_t)255;
        return p;
    };
    u16*   wf     = (u16*)alloc((size_t)(WF_C1 + 1024) * 2);
    u16*   s1out  = (u16*)alloc((size_t)800 * 42 * 42 * 16 * 2);
    float* z      = (float*)alloc((size_t)320 * D * 4);
    float* zp     = (float*)alloc((size_t)480 * D * 4);
    float* within = (float*)alloc(1280 * 4);
    float* crossb = (float*)alloc(1280 * 4);
    float* augb   = (float*)alloc(160 * 4);
    float* protos = (float*)alloc((size_t)20 * D * 4);
    float* dist   = (float*)alloc(6400 * 4);

    prep_weights<<<74, 256, 0, stream>>>(K[0], K[1], K[2], K[3], K[4], K[5], K[6], K[7], wf);

    stage1_kernel<<<800 * 6, 512, 0, stream>>>(sup, qry, B[0], wf,
                                               B[1], B[2], B[3], g1, be1, Wm, s1out);
    stage2_kernel<<<800, 512, 0, stream>>>(s1out, wf, B[4], B[5], B[6], B[7],
                                           g2, be2, Wm, z, zp);

    pairs_kernel<<<2720, 256, 0, stream>>>(z, within, crossb, augb);
    protos_kernel<<<(20 * D + 255) / 256, 256, 0, stream>>>(zp, protos);
    dists_kernel<<<6400, 256, 0, stream>>>(zp + (size_t)160 * D, protos, dist);
    final_kernel<<<1, 256, 0, stream>>>(dist, within, crossb, augb, out);
}

// Round 2
// 291.959 us; speedup vs baseline: 1.5068x; 1.1999x over previous
//
#include <hip/hip_runtime.h>
#include <math.h>

// ---------------------------------------------------------------------------
// Prototypical network forward on MI355X.
// Round 4: half-major LDS layout (ch-half h of pixel P at h*HALF + P*16) +
// 6-MFMA K=192 tap mapping so all B-fragment addresses are one VGPR base +
// compile-time ds_read immediates (taps t and t+L use the same offset list).
// Kills the per-tap swizzle address VALU (the 80% VALUBusy) and the LDS bank
// conflicts (contiguous 256B per 16-lane group).
//   image slots: [0,160) sup | [160,320) sup flipped | [320,800) pro(sup+qry)
// ---------------------------------------------------------------------------

typedef __attribute__((ext_vector_type(8))) short bf16x8;
typedef __attribute__((ext_vector_type(8))) unsigned short u16x8;
typedef __attribute__((ext_vector_type(4))) float f32x4;
typedef unsigned short u16;
typedef unsigned int u32;

#define PIX84 (84 * 84)      // 7056
#define D     (21 * 21 * 16) // 7056
#define WF_LAYER 3072        // u16 per conv2..8 layer: 6 steps * 64 lanes * 8
#define WF_C1 (7 * WF_LAYER) // 21504: offset (u16) of conv1 A-fragments

__device__ __forceinline__ float bf2f(u16 v) {
    union { u32 i; float f; } c; c.i = ((u32)v) << 16; return c.f;
}
__device__ __forceinline__ u16 f2bf(float f) {
    union { float f; u32 i; } c; c.f = f;
    u32 r = c.i + 0x7fffu + ((c.i >> 16) & 1u);
    return (u16)(r >> 16);
}
// Native bf16 pair conversion: compiler emits v_cvt_pk_bf16_f32 (RNE).
__device__ __forceinline__ u32 pack2(float a, float b) {
    union { __bf16 h[2]; u32 u; } p;
    p.h[0] = (__bf16)a; p.h[1] = (__bf16)b;
    return p.u;
}

// 16B LDS load with only 8B alignment guarantee (ds_read2_b64).
__device__ __forceinline__ bf16x8 ld_bf16x8_a8(const char* p) {
    union { uint2 q[2]; bf16x8 v; } u;
    u.q[0] = *(const uint2*)(p);
    u.q[1] = *(const uint2*)(p + 8);
    return u.v;
}

__device__ __forceinline__ float blockReduceSum(float v) {
    __shared__ float red[8];
    #pragma unroll
    for (int o = 32; o > 0; o >>= 1) v += __shfl_down(v, o, 64);
    const int lane = threadIdx.x & 63, wid = threadIdx.x >> 6;
    __syncthreads();
    if (lane == 0) red[wid] = v;
    __syncthreads();
    float r = 0.f;
    if (threadIdx.x == 0) {
        const int nw = (blockDim.x + 63) >> 6;
        for (int i = 0; i < nw; ++i) r += red[i];
    }
    return r;
}

// Pack conv2..conv8 weights (HWIO [tap][ci][co]) into MFMA A-fragment layout.
// 6 K-steps of 32; k = 8*(lane>>4) + j; t = k>>4 selects tap-stream, ci = k&15.
//   stream t=0: s -> tap s        (offsets {0,1,2,L,L+1,L+2})
//   stream t=1: s -> tap s+3 for s>=3 (same offsets shifted +L); s<3 = zero
// conv1 frags at WF_C1: 2 MFMAs, k = dh*16 + dw*4 + ci (m0: dh 0/1, m1: dh 2),
// zero weight on padded slots (ci==3, dw==3, m1 k>=12).
__global__ void prep_weights(const float* __restrict__ k1, const float* __restrict__ k2,
                             const float* __restrict__ k3, const float* __restrict__ k4,
                             const float* __restrict__ k5, const float* __restrict__ k6,
                             const float* __restrict__ k7, const float* __restrict__ k8,
                             u16* __restrict__ wf)
{
    const int idx = blockIdx.x * 256 + threadIdx.x;
    if (idx < WF_C1) {
        const int j = idx & 7, lane = (idx >> 3) & 63, r = idx >> 9;
        const int s = r % 6, L = r / 6;
        const float* ks[7] = { k2, k3, k4, k5, k6, k7, k8 };
        const int co = lane & 15, g = lane >> 4;
        const int k = g * 8 + j;
        const int t = k >> 4, ci = k & 15;
        float v = 0.f;
        if (t == 0)      v = ks[L][(s * 16 + ci) * 16 + co];        // taps 0..5
        else if (s >= 3) v = ks[L][((s + 3) * 16 + ci) * 16 + co];  // taps 6..8
        wf[idx] = f2bf(v);
    } else if (idx < WF_C1 + 1024) {
        const int t = idx - WF_C1;
        const int j = t & 7, lane = (t >> 3) & 63, m = t >> 9;
        const int co = lane & 15, g = lane >> 4;
        const int k = g * 8 + j;
        const int dh  = (m == 0) ? (k >> 4) : 2;
        const int rem = (m == 0) ? (k & 15) : k;
        const int dw = rem >> 2, ci = rem & 3;
        const float v = (rem < 12 && ci < 3) ? k1[((dh * 3 + dw) * 3 + ci) * 16 + co] : 0.f;
        wf[idx] = f2bf(v);
    }
}

// One 16ch->16ch conv layer, MFMA, in-place in the half-major LDS buffer.
// Each wave holds its full set of output tiles in registers across a barrier.
// Reads src rows [0, nrows+2) at (j+dh, w+dw); writes rows [dro, dro+nrows).
// B-fragment: base VGPR rb = (g&1)*HALF + (Pb + (g>>1)*LW)*16, six reads at
// compile-time immediates {0,16,32, LW*16, LW*16+16, LW*16+32}.
template <int W, int LW, int MAXT, int HALF>
__device__ __forceinline__ void conv_layer(char* buf, const u16* wfL,
                                           const float* bias, float scale,
                                           int nrows, int dro, int lane, int wv)
{
    const int g = lane >> 4, col = lane & 15;
    bf16x8 wfr[6];
    #pragma unroll
    for (int s = 0; s < 6; ++s) wfr[s] = ((const bf16x8*)wfL)[s * 64 + lane];
    const float4 bv = *(const float4*)(bias + g * 4);
    const float c0 = bv.x * scale, c1 = bv.y * scale;
    const float c2 = bv.z * scale, c3 = bv.w * scale;
    const int NPX = nrows * W;
    const int TC = (NPX + 15) >> 4;
    const int t0 = wv * MAXT;
    const int rb_const = (g & 1) * HALF + (g >> 1) * (LW * 16);
    const int wb_const = (g >> 1) * HALF + (g & 1) * 8 + (dro * LW + 1) * 16;

    f32x4 acc[MAXT];
    #pragma unroll
    for (int u = 0; u < MAXT; ++u) {
        const int t = t0 + u;
        if (t < TC) {
            const int px = t * 16 + col;
            const int p = (px < NPX) ? px : 0;
            const int j = p / W, w = p - j * W;
            const char* rb = buf + rb_const + (j * LW + w) * 16;
            f32x4 a = { 0.f, 0.f, 0.f, 0.f };
            a = __builtin_amdgcn_mfma_f32_16x16x32_bf16(wfr[0], *(const bf16x8*)(rb),                a, 0, 0, 0);
            a = __builtin_amdgcn_mfma_f32_16x16x32_bf16(wfr[1], *(const bf16x8*)(rb + 16),           a, 0, 0, 0);
            a = __builtin_amdgcn_mfma_f32_16x16x32_bf16(wfr[2], *(const bf16x8*)(rb + 32),           a, 0, 0, 0);
            a = __builtin_amdgcn_mfma_f32_16x16x32_bf16(wfr[3], *(const bf16x8*)(rb + LW * 16),      a, 0, 0, 0);
            a = __builtin_amdgcn_mfma_f32_16x16x32_bf16(wfr[4], *(const bf16x8*)(rb + LW * 16 + 16), a, 0, 0, 0);
            a = __builtin_amdgcn_mfma_f32_16x16x32_bf16(wfr[5], *(const bf16x8*)(rb + LW * 16 + 32), a, 0, 0, 0);
            acc[u] = a;
        }
    }
    __syncthreads();   // all reads done before any in-place write
    #pragma unroll
    for (int u = 0; u < MAXT; ++u) {
        const int t = t0 + u;
        if (t < TC) {
            const int px = t * 16 + col;
            if (px < NPX) {
                const int j = px / W, w = px - j * W;
                const u32 lo = pack2(fmaf(acc[u][0], scale, c0), fmaf(acc[u][1], scale, c1));
                const u32 hi = pack2(fmaf(acc[u][2], scale, c2), fmaf(acc[u][3], scale, c3));
                *(uint2*)(buf + wb_const + (j * LW + w) * 16) = make_uint2(lo, hi);
            }
        }
    }
    __syncthreads();
}

// stage1: conv1(MFMA) + conv2/3/4(MFMA) + bn/relu/pool -> s1out (42x42x16 bf16)
// grid: img * 6 strips (7 pooled rows each). Single 20x86 LDS buffer, in-place.
#define NP1   (20 * 86)
#define HALF1 (NP1 * 16)     // 27520 B per channel-half
__global__ __launch_bounds__(512) void stage1_kernel(
    const float* __restrict__ sup, const float* __restrict__ qry,
    const float* __restrict__ b1,
    const u16* __restrict__ wf,
    const float* __restrict__ b2, const float* __restrict__ b3,
    const float* __restrict__ b4,
    const float* __restrict__ g1, const float* __restrict__ be1,
    const float* __restrict__ Wm,
    u16* __restrict__ s1out)
{
    __shared__ char buf[2 * HALF1];             // 55,040 B
    __shared__ u16 stag[(22 * 86 + 2) * 4];     // 15,152 B raw input, ch padded to 4
    const int img = blockIdx.x / 6, bb = blockIdx.x % 6;
    const int R0 = 14 * bb;              // base c4-row of this strip
    const int tid = threadIdx.x, lane = tid & 63, wv = tid >> 6;
    const bool pro = img >= 320;

    const float* src;
    bool flip = false;
    if (img < 160) src = sup + (size_t)img * (PIX84 * 3);
    else if (img < 320) { src = sup + (size_t)(img - 160) * (PIX84 * 3); flip = true; }
    else {
        const int m = img - 320;
        src = (m < 160) ? sup + (size_t)m * (PIX84 * 3)
                        : qry + (size_t)(m - 160) * (PIX84 * 3);
    }
    const float s1 = pro ? Wm[0] : 1.f, s2 = pro ? Wm[1] : 1.f;
    const float s3 = pro ? Wm[2] : 1.f, s4 = pro ? Wm[3] : 1.f;
    const float pre = pro ? Wm[4] : 1.f, rs = pro ? Wm[5] : 1.f;
    const float post = pro ? Wm[6] : 1.f;

    // zero border columns of conv buffer (rows 0..19, cols 0 & 85)
    for (int i = tid; i < 40; i += 512) {
        const int P = (i >> 1) * 86 + ((i & 1) ? 85 : 0);
        *(uint4*)(buf + P * 16) = make_uint4(0, 0, 0, 0);
        *(uint4*)(buf + HALF1 + P * 16) = make_uint4(0, 0, 0, 0);
    }

    // stage raw input rows R0-4 .. R0+17 as bf16, zero-padded borders.
    // stag px (r,c): input row hin=R0-4+r, col win=c-1; 4 u16/px (3 ch + pad).
    for (int p = tid; p < 22 * 86; p += 512) {
        const int r = p / 86, c = p - r * 86;
        const int hin = R0 - 4 + r, win = c - 1;
        u32 lo = 0, hi = 0;
        if ((unsigned)hin < 84u && (unsigned)win < 84u) {
            const int wsrc = flip ? (83 - win) : win;
            const float* ip = src + ((size_t)(hin * 84 + wsrc)) * 3;
            lo = pack2(ip[0], ip[1]);
            hi = pack2(ip[2], 0.f);
        }
        *(uint2*)((char*)stag + (size_t)p * 8) = make_uint2(lo, hi);
    }
    __syncthreads();

    // conv1 via MFMA: 105 tiles of 16 px. B-fragment per lane = two 8B reads:
    // m0 covers patch rows dh=0,1 (k=dh*16+dw*4+ci), m1 covers dh=2.
    {
        const int g = lane >> 4, col = lane & 15;
        const bf16x8 wA0 = ((const bf16x8*)(wf + WF_C1))[lane];
        const bf16x8 wA1 = ((const bf16x8*)(wf + WF_C1))[64 + lane];
        const float4 bv = *(const float4*)(b1 + g * 4);
        const int off0 = ((g >> 1) * 86 + (g & 1) * 2) * 8;
        const int off1 = (2 * 86 + (g & 1) * 2) * 8;
        const int wb_const = (g >> 1) * HALF1 + (g & 1) * 8;
        for (int t = wv; t < 105; t += 8) {
            const int p = t * 16 + col;          // 105*16 == 20*84 exactly
            const int ri = p / 84, w = p - ri * 84;
            const int base = (ri * 86 + w) * 8;
            const bf16x8 B0 = ld_bf16x8_a8((const char*)stag + base + off0);
            const bf16x8 B1 = ld_bf16x8_a8((const char*)stag + base + off1);
            f32x4 a = { 0.f, 0.f, 0.f, 0.f };
            a = __builtin_amdgcn_mfma_f32_16x16x32_bf16(wA0, B0, a, 0, 0, 0);
            a = __builtin_amdgcn_mfma_f32_16x16x32_bf16(wA1, B1, a, 0, 0, 0);
            const int h = R0 - 3 + ri;
            const float sc = ((unsigned)h < 84u) ? s1 : 0.f;  // OOB rows -> exact 0
            const u32 lo = pack2((a[0] + bv.x) * sc, (a[1] + bv.y) * sc);
            const u32 hi = pack2((a[2] + bv.z) * sc, (a[3] + bv.w) * sc);
            *(uint2*)(buf + wb_const + (ri * 86 + (w + 1)) * 16) = make_uint2(lo, hi);
        }
    }
    __syncthreads();

    conv_layer<84, 86, 12, HALF1>(buf, wf,                b2, s2, 18, 0, lane, wv);  // c2
    conv_layer<84, 86, 11, HALF1>(buf, wf + WF_LAYER,     b3, s3, 16, 0, lane, wv);  // c3
    conv_layer<84, 86, 10, HALF1>(buf, wf + 2 * WF_LAYER, b4, s4, 14, 0, lane, wv);  // c4

    // bn + relu + 2x2 pool (scale-inside-max for sign-correctness) -> global
    for (int e = tid; e < 7 * 42 * 2; e += 512) {
        const int hf = e & 1;
        const int pc = (e >> 1) % 42, pr = (e >> 1) / 42;
        float mx[8];
        #pragma unroll
        for (int c = 0; c < 8; ++c) mx[c] = -1e30f;
        #pragma unroll
        for (int dy = 0; dy < 2; ++dy)
            #pragma unroll
            for (int dx = 0; dx < 2; ++dx) {
                const int P = (2 * pr + dy) * 86 + (2 * pc + dx + 1);
                const u16x8 vv = *(const u16x8*)(buf + hf * HALF1 + P * 16);
                #pragma unroll
                for (int c = 0; c < 8; ++c) {
                    const int ch = hf * 8 + c;
                    const float t =
                        rs * fmaxf(0.f, pre * fmaf(g1[ch], bf2f(vv[c]), be1[ch]));
                    mx[c] = fmaxf(mx[c], t);
                }
            }
        uint4 o;
        o.x = pack2(post * mx[0], post * mx[1]);
        o.y = pack2(post * mx[2], post * mx[3]);
        o.z = pack2(post * mx[4], post * mx[5]);
        o.w = pack2(post * mx[6], post * mx[7]);
        *(uint4*)(s1out + (size_t)img * 28224 +
                  ((size_t)(7 * bb + pr) * 42 + pc) * 16 + hf * 8) = o;
    }
}

// stage2: whole 42x42 image in LDS; conv5..8 in-place; bn+pool -> z/zp (f32)
#define NP2   (44 * 44)
#define HALF2 (NP2 * 16)     // 30976 B per channel-half
__global__ __launch_bounds__(512) void stage2_kernel(
    const u16* __restrict__ s1in, const u16* __restrict__ wf,
    const float* __restrict__ b5, const float* __restrict__ b6,
    const float* __restrict__ b7, const float* __restrict__ b8,
    const float* __restrict__ g2, const float* __restrict__ be2,
    const float* __restrict__ Wm,
    float* __restrict__ z, float* __restrict__ zp)
{
    __shared__ char buf[2 * HALF2];   // 61,952 B
    const int img = blockIdx.x;
    const int tid = threadIdx.x, lane = tid & 63, wv = tid >> 6;
    const bool pro = img >= 320;
    const float s5 = pro ? Wm[7] : 1.f, s6 = pro ? Wm[8] : 1.f;
    const float s7 = pro ? Wm[9] : 1.f, s8 = pro ? Wm[10] : 1.f;
    const float pre = pro ? Wm[11] : 1.f, rs = pro ? Wm[12] : 1.f;
    const float post = pro ? (Wm[13] * Wm[14]) : 1.f;

    // zero border ring
    for (int i = tid; i < 44 * 44; i += 512) {
        const int r = i / 44, c = i - r * 44;
        if (r == 0 || r == 43 || c == 0 || c == 43) {
            *(uint4*)(buf + i * 16) = make_uint4(0, 0, 0, 0);
            *(uint4*)(buf + HALF2 + i * 16) = make_uint4(0, 0, 0, 0);
        }
    }
    // load 42x42x16 bf16 input into interior
    const u16* ip = s1in + (size_t)img * 28224;
    for (int cix = tid; cix < 42 * 42 * 2; cix += 512) {
        const int Pi = cix >> 1, hf = cix & 1;
        const int r = Pi / 42, c = Pi - r * 42;
        const uint4 v = *(const uint4*)(ip + (size_t)cix * 8);
        *(uint4*)(buf + hf * HALF2 + ((r + 1) * 44 + (c + 1)) * 16) = v;
    }
    __syncthreads();

    conv_layer<42, 44, 14, HALF2>(buf, wf + 3 * WF_LAYER, b5, s5, 42, 1, lane, wv);  // c5
    conv_layer<42, 44, 14, HALF2>(buf, wf + 4 * WF_LAYER, b6, s6, 42, 1, lane, wv);  // c6
    conv_layer<42, 44, 14, HALF2>(buf, wf + 5 * WF_LAYER, b7, s7, 42, 1, lane, wv);  // c7
    conv_layer<42, 44, 14, HALF2>(buf, wf + 6 * WF_LAYER, b8, s8, 42, 1, lane, wv);  // c8

    float* outp = pro ? (zp + (size_t)(img - 320) * D) : (z + (size_t)img * D);
    for (int e = tid; e < 21 * 21 * 2; e += 512) {
        const int hf = e & 1;
        const int pc = (e >> 1) % 21, pr = (e >> 1) / 21;
        float mx[8];
        #pragma unroll
        for (int c = 0; c < 8; ++c) mx[c] = -1e30f;
        #pragma unroll
        for (int dy = 0; dy < 2; ++dy)
            #pragma unroll
            for (int dx = 0; dx < 2; ++dx) {
                const int P = (2 * pr + dy + 1) * 44 + (2 * pc + dx + 1);
                const u16x8 vv = *(const u16x8*)(buf + hf * HALF2 + P * 16);
                #pragma unroll
                for (int c = 0; c < 8; ++c) {
                    const int ch = hf * 8 + c;
                    const float t =
                        rs * fmaxf(0.f, pre * fmaf(g2[ch], bf2f(vv[c]), be2[ch]));
                    mx[c] = fmaxf(mx[c], t);
                }
            }
        float* op = outp + ((size_t)(pr * 21 + pc)) * 16 + hf * 8;
        float4 o0 = make_float4(post * mx[0], post * mx[1], post * mx[2], post * mx[3]);
        float4 o1 = make_float4(post * mx[4], post * mx[5], post * mx[6], post * mx[7]);
        *(float4*)op = o0;
        *(float4*)(op + 4) = o1;
    }
}

// Pairwise (mean squared distance)^2 over z (320 f32 rows).
__global__ void pairs_kernel(const float* __restrict__ z,
                             float* __restrict__ within, float* __restrict__ cross,
                             float* __restrict__ aug)
{
    const int bid = blockIdx.x;
    const float *u, *v;
    float* dst;
    if (bid < 1280) {
        const int c = bid / 64, i = (bid % 64) / 8, j = bid % 8;
        u = z + (size_t)(c * 8 + i) * D;
        v = z + (size_t)(c * 8 + j) * D;
        dst = within + bid;
    } else if (bid < 2560) {
        const int t = bid - 1280;
        const int c = t / 64, i = (t % 64) / 8, j = t % 8;
        const int c2 = (c + 1) % 20;
        u = z + (size_t)(c * 8 + i) * D;
        v = z + (size_t)(c2 * 8 + j) * D;
        dst = cross + t;
    } else {
        const int t = bid - 2560;
        u = z + (size_t)t * D;
        v = z + (size_t)(160 + t) * D;
        dst = aug + t;
    }
    const float4* u4 = (const float4*)u;
    const float4* v4 = (const float4*)v;
    float s = 0.f;
    for (int d = threadIdx.x; d < D / 4; d += 256) {
        const float4 a = u4[d], b = v4[d];
        const float dx = a.x - b.x, dy = a.y - b.y, dz = a.z - b.z, dw = a.w - b.w;
        s += dx * dx + dy * dy + dz * dz + dw * dw;
    }
    s = blockReduceSum(s);
    if (threadIdx.x == 0) {
        const float m = s / (float)D;
        *dst = m * m;
    }
}

__global__ void protos_kernel(const float* __restrict__ zp, float* __restrict__ protos)
{
    const int idx = blockIdx.x * 256 + threadIdx.x;
    if (idx >= 20 * D) return;
    const int c = idx / D, d = idx % D;
    float s = 0.f;
    #pragma unroll
    for (int i = 0; i < 8; ++i) s += zp[(size_t)(c * 8 + i) * D + d];
    protos[idx] = s * 0.125f;
}

__global__ void dists_kernel(const float* __restrict__ zq, const float* __restrict__ protos,
                             float* __restrict__ dists)
{
    const int q = blockIdx.x / 20, c = blockIdx.x % 20;
    const float4* u4 = (const float4*)(zq + (size_t)q * D);
    const float4* v4 = (const float4*)(protos + (size_t)c * D);
    float s = 0.f;
    for (int d = threadIdx.x; d < D / 4; d += 256) {
        const float4 a = u4[d], b = v4[d];
        const float dx = a.x - b.x, dy = a.y - b.y, dz = a.z - b.z, dw = a.w - b.w;
        s += dx * dx + dy * dy + dz * dz + dw * dw;
    }
    s = blockReduceSum(s);
    if (threadIdx.x == 0) dists[blockIdx.x] = s / (float)D;
}

__global__ void final_kernel(const float* __restrict__ dists,
                             const float* __restrict__ within,
                             const float* __restrict__ cross,
                             const float* __restrict__ aug,
                             float* __restrict__ out)
{
    float ce = 0.f, accv = 0.f, uns = 0.f;
    for (int r = threadIdx.x; r < 320; r += 256) {
        const float* dr = dists + r * 20;
        const int y = r / 16;
        float dmin = dr[0];
        int amin = 0;
        float m = -dr[0];
        #pragma unroll
        for (int j = 1; j < 20; ++j) {
            if (dr[j] < dmin) { dmin = dr[j]; amin = j; }
            m = fmaxf(m, -dr[j]);
        }
        float se = 0.f;
        #pragma unroll
        for (int j = 0; j < 20; ++j) se += expf(-dr[j] - m);
        const float lse = m + logf(se);
        ce += dr[y] + lse;
        accv += (amin == y) ? 1.0f : 0.0f;
    }
    for (int i = threadIdx.x; i < 1280; i += 256) uns += within[i] - cross[i];
    for (int i = threadIdx.x; i < 160; i += 256) uns += aug[i];

    ce = blockReduceSum(ce);
    accv = blockReduceSum(accv);
    uns = blockReduceSum(uns);
    if (threadIdx.x == 0) {
        out[0] = ce / 320.0f + uns / 17.0f + 80.0f;   // 0.5 * 160
        out[1] = accv / 320.0f;
    }
}

extern "C" void kernel_launch(void* const* d_in, const int* in_sizes, int n_in,
                              void* d_out, int out_size, void* d_ws, size_t ws_size,
                              hipStream_t stream)
{
    (void)in_sizes; (void)n_in; (void)out_size; (void)ws_size;
    const float* sup = (const float*)d_in[0];
    const float* qry = (const float*)d_in[1];
    const float* K[8]; for (int i = 0; i < 8; ++i) K[i] = (const float*)d_in[2 + i];
    const float* B[8]; for (int i = 0; i < 8; ++i) B[i] = (const float*)d_in[10 + i];
    const float* g1  = (const float*)d_in[18];
    const float* be1 = (const float*)d_in[19];
    const float* g2  = (const float*)d_in[20];
    const float* be2 = (const float*)d_in[21];
    const float* Wm  = (const float*)d_in[22];
    float* out = (float*)d_out;

    // ---- workspace carve-up (~68 MB total) ----
    size_t off = 0;
    auto alloc = [&](size_t bytes) -> void* {
        void* p = (char*)d_ws + off;
        off += (bytes + 255) & ~(size_t)255;
        return p;
    };
    u16*   wf     = (u16*)alloc((size_t)(WF_C1 + 1024) * 2);
    u16*   s1out  = (u16*)alloc((size_t)800 * 42 * 42 * 16 * 2);
    float* z      = (float*)alloc((size_t)320 * D * 4);
    float* zp     = (float*)alloc((size_t)480 * D * 4);
    float* within = (float*)alloc(1280 * 4);
    float* crossb = (float*)alloc(1280 * 4);
    float* augb   = (float*)alloc(160 * 4);
    float* protos = (float*)alloc((size_t)20 * D * 4);
    float* dist   = (float*)alloc(6400 * 4);

    prep_weights<<<(WF_C1 + 1024 + 255) / 256, 256, 0, stream>>>(
        K[0], K[1], K[2], K[3], K[4], K[5], K[6], K[7], wf);

    stage1_kernel<<<800 * 6, 512, 0, stream>>>(sup, qry, B[0], wf,
                                               B[1], B[2], B[3], g1, be1, Wm, s1out);
    stage2_kernel<<<800, 512, 0, stream>>>(s1out, wf, B[4], B[5], B[6], B[7],
                                           g2, be2, Wm, z, zp);

    pairs_kernel<<<2720, 256, 0, stream>>>(z, within, crossb, augb);
    protos_kernel<<<(20 * D + 255) / 256, 256, 0, stream>>>(zp, protos);
    dists_kernel<<<6400, 256, 0, stream>>>(zp + (size_t)160 * D, protos, dist);
    final_kernel<<<1, 256, 0, stream>>>(dist, within, crossb, augb, out);
}